// Round 1
// baseline (11106.449 us; speedup 1.0000x reference)
//
#include <hip/hip_runtime.h>
#include <math.h>

#define LNUM 6
#define H 8
#define DM 512
#define DH 64
#define DI 2048
#define QLEN 256
#define BSZ 32
#define MLEN 256
#define KLEN (QLEN + MLEN)   // 512
#define EPS 1e-5f
#define SCALE 0.125f         // 1/sqrt(64)

// ---------------- GEMM: C[M,N] = A[M,K] @ B[K,N], fp32 tiled ----------------
#define BM 64
#define BN 64
#define BK 16

enum { EP_PLAIN = 0, EP_BIAS = 1, EP_BIAS_RELU = 2, EP_QKV = 3, EP_RK = 4 };

__global__ __launch_bounds__(256) void gemm_kernel(
    const float* __restrict__ A0, const float* __restrict__ A1, int split,
    const float* __restrict__ B, float* __restrict__ C,
    int M, int N, int K, int mode,
    const float* __restrict__ bias,
    float* __restrict__ oq, float* __restrict__ ok, float* __restrict__ ov)
{
    __shared__ float As[BK][BM + 4];   // stride 68 floats (16B-aligned rows, no bad banks)
    __shared__ float Bs[BK][BN + 4];

    const int tid = threadIdx.x;
    const int tx = tid & 15, ty = tid >> 4;
    const int m0 = blockIdx.y * BM, n0 = blockIdx.x * BN;

    float acc[4][4] = {};

    const int arow = tid >> 2;          // 0..63
    const int acol = (tid & 3) * 4;     // 0,4,8,12
    const int brow = tid >> 4;          // 0..15
    const int bcol = (tid & 15) * 4;    // 0..60

    const int gm = m0 + arow;
    const float* Arow = (gm < split) ? (A0 + (size_t)gm * K)
                                     : (A1 + (size_t)(gm - split) * K);

    for (int k0 = 0; k0 < K; k0 += BK) {
        const float4 av = *(const float4*)(Arow + k0 + acol);
        const float4 bv = *(const float4*)(B + (size_t)(k0 + brow) * N + n0 + bcol);
        __syncthreads();
        As[acol + 0][arow] = av.x;
        As[acol + 1][arow] = av.y;
        As[acol + 2][arow] = av.z;
        As[acol + 3][arow] = av.w;
        *(float4*)&Bs[brow][bcol] = bv;
        __syncthreads();
#pragma unroll
        for (int kk = 0; kk < BK; kk++) {
            const float4 a = *(const float4*)&As[kk][ty * 4];
            const float4 b = *(const float4*)&Bs[kk][tx * 4];
            acc[0][0] += a.x * b.x; acc[0][1] += a.x * b.y; acc[0][2] += a.x * b.z; acc[0][3] += a.x * b.w;
            acc[1][0] += a.y * b.x; acc[1][1] += a.y * b.y; acc[1][2] += a.y * b.z; acc[1][3] += a.y * b.w;
            acc[2][0] += a.z * b.x; acc[2][1] += a.z * b.y; acc[2][2] += a.z * b.z; acc[2][3] += a.z * b.w;
            acc[3][0] += a.w * b.x; acc[3][1] += a.w * b.y; acc[3][2] += a.w * b.z; acc[3][3] += a.w * b.w;
        }
    }

    const int mbase = m0 + ty * 4, nbase = n0 + tx * 4;
    if (mode <= EP_BIAS_RELU) {
        float4 bb = make_float4(0.f, 0.f, 0.f, 0.f);
        if (mode >= EP_BIAS) bb = *(const float4*)(bias + nbase);
#pragma unroll
        for (int ii = 0; ii < 4; ii++) {
            float4 o;
            o.x = acc[ii][0] + bb.x;
            o.y = acc[ii][1] + bb.y;
            o.z = acc[ii][2] + bb.z;
            o.w = acc[ii][3] + bb.w;
            if (mode == EP_BIAS_RELU) {
                o.x = fmaxf(o.x, 0.f); o.y = fmaxf(o.y, 0.f);
                o.z = fmaxf(o.z, 0.f); o.w = fmaxf(o.w, 0.f);
            }
            *(float4*)&C[(size_t)(mbase + ii) * N + nbase] = o;
        }
    } else if (mode == EP_QKV) {
        // row m -> (kl, b); col n -> sec(q/k/v), head, d
#pragma unroll
        for (int ii = 0; ii < 4; ii++) {
            const int mm = mbase + ii;
            const int kl = mm >> 5;        // /BSZ
            const int b_ = mm & 31;
#pragma unroll
            for (int jj = 0; jj < 4; jj++) {
                const int nn = nbase + jj;
                const int sec = nn >> 9;           // /512
                const int cc = nn & 511;
                const int hd = cc >> 6;
                const int dd = cc & 63;
                const float val = acc[ii][jj];
                const size_t bh = (size_t)b_ * H + hd;
                if (sec == 1)      ok[(bh * KLEN + kl) * DH + dd] = val;
                else if (sec == 2) ov[(bh * KLEN + kl) * DH + dd] = val;
                else if (kl >= MLEN) oq[(bh * QLEN + (kl - MLEN)) * DH + dd] = val;
            }
        }
    } else {  // EP_RK: C used as rk[H][KLEN][DH], row m = position jj
#pragma unroll
        for (int ii = 0; ii < 4; ii++) {
            const int mm = mbase + ii;
#pragma unroll
            for (int jj = 0; jj < 4; jj++) {
                const int nn = nbase + jj;
                const int hd = nn >> 6;
                const int dd = nn & 63;
                C[((size_t)hd * KLEN + mm) * DH + dd] = acc[ii][jj];
            }
        }
    }
}

// ---------------- positional embedding r[KLEN][DM] ----------------
__global__ __launch_bounds__(256) void r_kernel(float* __restrict__ r)
{
    const int idx = blockIdx.x * 256 + threadIdx.x;   // 512*512 total
    const int p = idx >> 9;       // row
    const int c = idx & 511;      // col
    const float pos = (float)(KLEN - 1 - p);
    const int i2 = (c < 256) ? c : (c - 256);
    const float invf = expf(-((float)(2 * i2) / (float)DM) * logf(10000.0f));
    const float a = pos * invf;
    r[idx] = (c < 256) ? sinf(a) : cosf(a);
}

// ---------------- row-dot: out[row] = mat[row,:] . bvec[head(row),:] ----------------
__global__ __launch_bounds__(256) void rowdot_kernel(
    const float* __restrict__ mat, const float* __restrict__ bvec,
    float* __restrict__ out, int nrows)
{
    const int w = (int)((blockIdx.x * 256 + threadIdx.x) >> 6);  // wave id = row
    const int lane = threadIdx.x & 63;
    if (w >= nrows) return;
    const int hd = (w >> 9) & 7;   // works for both [b*H+n][KLEN] and [n][KLEN]
    float val = mat[(size_t)w * DH + lane] * bvec[hd * DH + lane];
#pragma unroll
    for (int off = 32; off > 0; off >>= 1) val += __shfl_down(val, off, 64);
    if (lane == 0) out[w] = val;
}

// ---------------- attention: one block per (b,n), one thread per query row ----------------
#define TJ 16
__global__ __launch_bounds__(256) void attn_kernel(
    const float* __restrict__ q, const float* __restrict__ kmat, const float* __restrict__ vmat,
    const float* __restrict__ rk, const float* __restrict__ biask, const float* __restrict__ biasr,
    float* __restrict__ vec)
{
    const int bn = blockIdx.x;           // b*H + n
    const int n = bn & 7;
    const int i = threadIdx.x;           // query row

    const float* kb = kmat + (size_t)bn * KLEN * DH;
    const float* vb = vmat + (size_t)bn * KLEN * DH;
    const float* rkb = rk + (size_t)n * KLEN * DH;
    const float* bkr = biask + (size_t)bn * KLEN;
    const float* brr = biasr + (size_t)n * KLEN;

    float4 qf[16];
    const float4* q4 = (const float4*)(q + ((size_t)bn * QLEN + i) * DH);
#pragma unroll
    for (int u = 0; u < 16; u++) qf[u] = q4[u];

    __shared__ float Ks[TJ][DH];
    __shared__ float Vs[TJ][DH];
    __shared__ float bks[TJ];

    float m = -1e30f, l = 0.f;
    float acc[DH];
#pragma unroll
    for (int d = 0; d < DH; d++) acc[d] = 0.f;

    for (int j0 = 0; j0 < KLEN; j0 += TJ) {
        __syncthreads();
        {
            const int t = threadIdx.x;
            const int jt = t >> 4;
            const int d4 = (t & 15) * 4;
            *(float4*)&Ks[jt][d4] = *(const float4*)&kb[(size_t)(j0 + jt) * DH + d4];
            *(float4*)&Vs[jt][d4] = *(const float4*)&vb[(size_t)(j0 + jt) * DH + d4];
            if (t < TJ) bks[t] = bkr[j0 + t];
        }
        __syncthreads();

        float p[TJ];
#pragma unroll
        for (int jt = 0; jt < TJ; jt++) {
            const int j = j0 + jt;
            const int jjx = j + (QLEN - 1) - i;
            float sc = -1e30f;
            if (jjx < KLEN) {
                const float4* rk4 = (const float4*)(rkb + (size_t)jjx * DH);
                float k0 = 0.f, k1 = 0.f, k2 = 0.f, k3 = 0.f;
                float r0 = 0.f, r1 = 0.f, r2 = 0.f, r3 = 0.f;
#pragma unroll
                for (int u = 0; u < 16; u++) {
                    const float4 kv = *(const float4*)&Ks[jt][u * 4];
                    const float4 rv = rk4[u];
                    k0 += qf[u].x * kv.x; k1 += qf[u].y * kv.y;
                    k2 += qf[u].z * kv.z; k3 += qf[u].w * kv.w;
                    r0 += qf[u].x * rv.x; r1 += qf[u].y * rv.y;
                    r2 += qf[u].z * rv.z; r3 += qf[u].w * rv.w;
                }
                sc = ((k0 + k1) + (k2 + k3) + (r0 + r1) + (r2 + r3)
                      + bks[jt] + brr[jjx]) * SCALE;
            }
            p[jt] = sc;
        }

        float mt = m;
#pragma unroll
        for (int jt = 0; jt < TJ; jt++) mt = fmaxf(mt, p[jt]);
        const float f = __expf(m - mt);
        float ps = 0.f;
#pragma unroll
        for (int jt = 0; jt < TJ; jt++) { p[jt] = __expf(p[jt] - mt); ps += p[jt]; }
        l = l * f + ps;
        m = mt;

#pragma unroll
        for (int u = 0; u < 16; u++) {
            float t0 = 0.f, t1 = 0.f, t2 = 0.f, t3 = 0.f;
#pragma unroll
            for (int jt = 0; jt < TJ; jt++) {
                const float4 vv = *(const float4*)&Vs[jt][u * 4];
                t0 += p[jt] * vv.x; t1 += p[jt] * vv.y;
                t2 += p[jt] * vv.z; t3 += p[jt] * vv.w;
            }
            acc[u * 4 + 0] = acc[u * 4 + 0] * f + t0;
            acc[u * 4 + 1] = acc[u * 4 + 1] * f + t1;
            acc[u * 4 + 2] = acc[u * 4 + 2] * f + t2;
            acc[u * 4 + 3] = acc[u * 4 + 3] * f + t3;
        }
    }

    const float inv = 1.f / l;
    const int b_ = bn >> 3;
    float* out = vec + ((size_t)i * BSZ + b_) * (H * DH) + n * DH;
#pragma unroll
    for (int u = 0; u < 16; u++) {
        float4 o;
        o.x = acc[u * 4 + 0] * inv; o.y = acc[u * 4 + 1] * inv;
        o.z = acc[u * 4 + 2] * inv; o.w = acc[u * 4 + 3] * inv;
        *(float4*)&out[u * 4] = o;
    }
}

// ---------------- fused residual + LayerNorm (in place on h) ----------------
__global__ __launch_bounds__(256) void ln_kernel(
    float* __restrict__ h, const float* __restrict__ add,
    const float* __restrict__ g, const float* __restrict__ b)
{
    const int row = blockIdx.x;
    const int t = threadIdx.x;
    const size_t base = (size_t)row * DM;
    const float x0 = h[base + t] + add[base + t];
    const float x1 = h[base + t + 256] + add[base + t + 256];
    float s = x0 + x1;
    float s2 = x0 * x0 + x1 * x1;
#pragma unroll
    for (int off = 32; off > 0; off >>= 1) {
        s += __shfl_down(s, off, 64);
        s2 += __shfl_down(s2, off, 64);
    }
    __shared__ float ws1[4], ws2[4];
    const int wid = t >> 6, lane = t & 63;
    if (lane == 0) { ws1[wid] = s; ws2[wid] = s2; }
    __syncthreads();
    __shared__ float mv[2];
    if (t == 0) {
        float a = 0.f, a2 = 0.f;
        for (int w = 0; w < 4; w++) { a += ws1[w]; a2 += ws2[w]; }
        const float mean = a / (float)DM;
        mv[0] = mean;
        mv[1] = rsqrtf(a2 / (float)DM - mean * mean + EPS);
    }
    __syncthreads();
    const float mean = mv[0], rstd = mv[1];
    h[base + t] = (x0 - mean) * rstd * g[t] + b[t];
    h[base + t + 256] = (x1 - mean) * rstd * g[t + 256] + b[t + 256];
}

// ---------------- launcher ----------------
extern "C" void kernel_launch(void* const* d_in, const int* in_sizes, int n_in,
                              void* d_out, int out_size, void* d_ws, size_t ws_size,
                              hipStream_t stream)
{
    const float* w      = (const float*)d_in[0];
    const float* mems   = (const float*)d_in[1];
    const float* qkv_w  = (const float*)d_in[2];
    const float* rnet_w = (const float*)d_in[3];
    const float* o_w    = (const float*)d_in[4];
    const float* ln1_g  = (const float*)d_in[5];
    const float* ln1_b  = (const float*)d_in[6];
    const float* ff_w1  = (const float*)d_in[7];
    const float* ff_b1  = (const float*)d_in[8];
    const float* ff_w2  = (const float*)d_in[9];
    const float* ff_b2  = (const float*)d_in[10];
    const float* ln2_g  = (const float*)d_in[11];
    const float* ln2_b  = (const float*)d_in[12];
    const float* rwb    = (const float*)d_in[13];
    const float* rrb    = (const float*)d_in[14];

    // workspace layout (floats); aliases: attn_tmp=q, ff1=k(+v), ff2tmp=vec
    float* hbuf  = (float*)d_ws;                       // 4,194,304
    float* rbuf  = hbuf + (size_t)QLEN * BSZ * DM;     //   262,144
    float* qbuf  = rbuf + (size_t)KLEN * DM;           // 4,194,304
    float* kbuf  = qbuf + (size_t)BSZ * H * QLEN * DH; // 8,388,608
    float* vbuf  = kbuf + (size_t)BSZ * H * KLEN * DH; // 8,388,608
    float* rkbuf = vbuf + (size_t)BSZ * H * KLEN * DH; //   262,144
    float* bkbuf = rkbuf + (size_t)H * KLEN * DH;      //   131,072
    float* brbuf = bkbuf + (size_t)BSZ * H * KLEN;     //     4,096
    float* vecb  = brbuf + (size_t)H * KLEN;           // 4,194,304
    float* atmp  = qbuf;   // alias
    float* ff1   = kbuf;   // alias (spans kbuf+vbuf = 16,777,216)
    float* ff2t  = vecb;   // alias

    hipMemcpyAsync(hbuf, w, (size_t)QLEN * BSZ * DM * sizeof(float),
                   hipMemcpyDeviceToDevice, stream);
    r_kernel<<<(KLEN * DM) / 256, 256, 0, stream>>>(rbuf);

    const int BIG = 1 << 30;
    for (int l = 0; l < LNUM; l++) {
        // QKV: [KLEN*BSZ, DM] @ [DM, 1536] with concat(mems[l], h) rows, scatter epilogue
        gemm_kernel<<<dim3((3 * H * DH) / BN, (KLEN * BSZ) / BM), 256, 0, stream>>>(
            mems + (size_t)l * MLEN * BSZ * DM, hbuf, MLEN * BSZ,
            qkv_w + (size_t)l * DM * 3 * H * DH, nullptr,
            KLEN * BSZ, 3 * H * DH, DM, EP_QKV, nullptr, qbuf, kbuf, vbuf);
        // r_head_k: [KLEN, DM] @ [DM, H*DH], scatter to rk[H][KLEN][DH]
        gemm_kernel<<<dim3((H * DH) / BN, KLEN / BM), 256, 0, stream>>>(
            rbuf, rbuf, BIG, rnet_w + (size_t)l * DM * H * DH, rkbuf,
            KLEN, H * DH, DM, EP_RK, nullptr, nullptr, nullptr, nullptr);
        // bias dots
        rowdot_kernel<<<(BSZ * H * KLEN * 64) / 256, 256, 0, stream>>>(
            kbuf, rwb, bkbuf, BSZ * H * KLEN);
        rowdot_kernel<<<(H * KLEN * 64) / 256, 256, 0, stream>>>(
            rkbuf, rrb, brbuf, H * KLEN);
        // attention
        attn_kernel<<<BSZ * H, 256, 0, stream>>>(qbuf, kbuf, vbuf, rkbuf, bkbuf, brbuf, vecb);
        // O projection
        gemm_kernel<<<dim3(DM / BN, (QLEN * BSZ) / BM), 256, 0, stream>>>(
            vecb, vecb, BIG, o_w + (size_t)l * H * DH * DM, atmp,
            QLEN * BSZ, DM, H * DH, EP_PLAIN, nullptr, nullptr, nullptr, nullptr);
        ln_kernel<<<QLEN * BSZ, 256, 0, stream>>>(hbuf, atmp, ln1_g + l * DM, ln1_b + l * DM);
        // FF1 (+bias+relu)
        gemm_kernel<<<dim3(DI / BN, (QLEN * BSZ) / BM), 256, 0, stream>>>(
            hbuf, hbuf, BIG, ff_w1 + (size_t)l * DM * DI, ff1,
            QLEN * BSZ, DI, DM, EP_BIAS_RELU, ff_b1 + (size_t)l * DI,
            nullptr, nullptr, nullptr);
        // FF2 (+bias)
        gemm_kernel<<<dim3(DM / BN, (QLEN * BSZ) / BM), 256, 0, stream>>>(
            ff1, ff1, BIG, ff_w2 + (size_t)l * DI * DM, ff2t,
            QLEN * BSZ, DM, DI, EP_BIAS, ff_b2 + (size_t)l * DM,
            nullptr, nullptr, nullptr);
        ln_kernel<<<QLEN * BSZ, 256, 0, stream>>>(hbuf, ff2t, ln2_g + l * DM, ln2_b + l * DM);
    }
    hipMemcpyAsync(d_out, hbuf, (size_t)out_size * sizeof(float),
                   hipMemcpyDeviceToDevice, stream);
}

// Round 2
// 7351.369 us; speedup vs baseline: 1.5108x; 1.5108x over previous
//
#include <hip/hip_runtime.h>
#include <math.h>

#define LNUM 6
#define H 8
#define DM 512
#define DH 64
#define DI 2048
#define QLEN 256
#define BSZ 32
#define MLEN 256
#define KLEN (QLEN + MLEN)   // 512
#define EPS 1e-5f
#define SCALE 0.125f         // 1/sqrt(64)
#define SN 1024              // S row stride: [AC(512) | Srel(512)]

// ---------------- GEMM: C[M,N] = A[M,K] @ B[K,N], fp32 tiled ----------------
#define BM 64
#define BN 64
#define BK 16

enum { EP_PLAIN = 0, EP_BIAS = 1, EP_BIAS_RELU = 2, EP_QKV = 3, EP_RK = 4 };

__global__ __launch_bounds__(256) void gemm_kernel(
    const float* __restrict__ A0, const float* __restrict__ A1, int split,
    const float* __restrict__ B, float* __restrict__ C,
    int M, int N, int K, int mode,
    const float* __restrict__ bias,
    float* __restrict__ oqw, float* __restrict__ oqr,
    float* __restrict__ ok, float* __restrict__ ov,
    const float* __restrict__ rwb, const float* __restrict__ rrb)
{
    __shared__ float As[BK][BM + 4];
    __shared__ float Bs[BK][BN + 4];

    const int tid = threadIdx.x;
    const int tx = tid & 15, ty = tid >> 4;
    const int m0 = blockIdx.y * BM, n0 = blockIdx.x * BN;

    float acc[4][4] = {};

    const int arow = tid >> 2;          // 0..63
    const int acol = (tid & 3) * 4;     // 0,4,8,12
    const int brow = tid >> 4;          // 0..15
    const int bcol = (tid & 15) * 4;    // 0..60

    const int gm = m0 + arow;
    const float* Arow = (gm < split) ? (A0 + (size_t)gm * K)
                                     : (A1 + (size_t)(gm - split) * K);

    for (int k0 = 0; k0 < K; k0 += BK) {
        const float4 av = *(const float4*)(Arow + k0 + acol);
        const float4 bv = *(const float4*)(B + (size_t)(k0 + brow) * N + n0 + bcol);
        __syncthreads();
        As[acol + 0][arow] = av.x;
        As[acol + 1][arow] = av.y;
        As[acol + 2][arow] = av.z;
        As[acol + 3][arow] = av.w;
        *(float4*)&Bs[brow][bcol] = bv;
        __syncthreads();
#pragma unroll
        for (int kk = 0; kk < BK; kk++) {
            const float4 a = *(const float4*)&As[kk][ty * 4];
            const float4 b = *(const float4*)&Bs[kk][tx * 4];
            acc[0][0] += a.x * b.x; acc[0][1] += a.x * b.y; acc[0][2] += a.x * b.z; acc[0][3] += a.x * b.w;
            acc[1][0] += a.y * b.x; acc[1][1] += a.y * b.y; acc[1][2] += a.y * b.z; acc[1][3] += a.y * b.w;
            acc[2][0] += a.z * b.x; acc[2][1] += a.z * b.y; acc[2][2] += a.z * b.z; acc[2][3] += a.z * b.w;
            acc[3][0] += a.w * b.x; acc[3][1] += a.w * b.y; acc[3][2] += a.w * b.z; acc[3][3] += a.w * b.w;
        }
    }

    const int mbase = m0 + ty * 4, nbase = n0 + tx * 4;
    if (mode <= EP_BIAS_RELU) {
        float4 bb = make_float4(0.f, 0.f, 0.f, 0.f);
        if (mode >= EP_BIAS) bb = *(const float4*)(bias + nbase);
#pragma unroll
        for (int ii = 0; ii < 4; ii++) {
            float4 o;
            o.x = acc[ii][0] + bb.x;
            o.y = acc[ii][1] + bb.y;
            o.z = acc[ii][2] + bb.z;
            o.w = acc[ii][3] + bb.w;
            if (mode == EP_BIAS_RELU) {
                o.x = fmaxf(o.x, 0.f); o.y = fmaxf(o.y, 0.f);
                o.z = fmaxf(o.z, 0.f); o.w = fmaxf(o.w, 0.f);
            }
            *(float4*)&C[(size_t)(mbase + ii) * N + nbase] = o;
        }
    } else if (mode == EP_QKV) {
        // row m -> (kl, b); col n -> sec(q/k/v), head, d
#pragma unroll
        for (int ii = 0; ii < 4; ii++) {
            const int mm = mbase + ii;
            const int kl = mm >> 5;        // /BSZ
            const int b_ = mm & 31;
#pragma unroll
            for (int jj = 0; jj < 4; jj++) {
                const int nn = nbase + jj;
                const int sec = nn >> 9;           // /512
                const int cc = nn & 511;
                const int hd = cc >> 6;
                const int dd = cc & 63;
                const float val = acc[ii][jj];
                const size_t bh = (size_t)b_ * H + hd;
                if (sec == 1)      ok[(bh * KLEN + kl) * DH + dd] = val;
                else if (sec == 2) ov[(bh * KLEN + kl) * DH + dd] = val;
                else if (kl >= MLEN) {
                    const size_t qi = (bh * QLEN + (kl - MLEN)) * DH + dd;
                    oqw[qi] = val + rwb[hd * DH + dd];   // q + r_w_bias
                    oqr[qi] = val + rrb[hd * DH + dd];   // q + r_r_bias
                }
            }
        }
    } else {  // EP_RK: C used as rk[H][KLEN][DH], row m = position jj
#pragma unroll
        for (int ii = 0; ii < 4; ii++) {
            const int mm = mbase + ii;
#pragma unroll
            for (int jj = 0; jj < 4; jj++) {
                const int nn = nbase + jj;
                const int hd = nn >> 6;
                const int dd = nn & 63;
                C[((size_t)hd * KLEN + mm) * DH + dd] = acc[ii][jj];
            }
        }
    }
}

// ---------------- positional embedding r[KLEN][DM] ----------------
__global__ __launch_bounds__(256) void r_kernel(float* __restrict__ r)
{
    const int idx = blockIdx.x * 256 + threadIdx.x;   // 512*512 total
    const int p = idx >> 9;       // row
    const int c = idx & 511;      // col
    const float pos = (float)(KLEN - 1 - p);
    const int i2 = (c < 256) ? c : (c - 256);
    const float invf = expf(-((float)(2 * i2) / (float)DM) * logf(10000.0f));
    const float a = pos * invf;
    r[idx] = (c < 256) ? sinf(a) : cosf(a);
}

// -------- batched score GEMM (NT): S[bnLoc][i][nOff+j] = A[bn][i,:]·B[bn or n][j,:] --------
// A: [256 bn][QLEN][DH]; B rows of DH floats; C = sbuf chunk [CH][QLEN][SN]
__global__ __launch_bounds__(256) void score_gemm(
    const float* __restrict__ Abase, const float* __restrict__ Bbase,
    int bPerHead, float* __restrict__ S, int nOff, int bnBase)
{
    __shared__ float As[BK][BM + 4];
    __shared__ float Bs[BK][BN + 4];

    const int bnLoc = blockIdx.z;
    const int bn = bnBase + bnLoc;
    const float* Aq = Abase + (size_t)bn * QLEN * DH;
    const float* Bq = Bbase + (size_t)(bPerHead ? (bn & 7) : bn) * KLEN * DH;
    float* Srow = S + (size_t)bnLoc * QLEN * SN;

    const int tid = threadIdx.x;
    const int tx = tid & 15, ty = tid >> 4;
    const int m0 = blockIdx.y * BM, n0 = blockIdx.x * BN;

    float acc[4][4] = {};
    const int row64 = tid >> 2;         // 0..63
    const int col4 = (tid & 3) * 4;     // 0,4,8,12

    for (int k0 = 0; k0 < DH; k0 += BK) {
        const float4 av = *(const float4*)(Aq + (size_t)(m0 + row64) * DH + k0 + col4);
        const float4 bv = *(const float4*)(Bq + (size_t)(n0 + row64) * DH + k0 + col4);
        __syncthreads();
        As[col4 + 0][row64] = av.x;
        As[col4 + 1][row64] = av.y;
        As[col4 + 2][row64] = av.z;
        As[col4 + 3][row64] = av.w;
        Bs[col4 + 0][row64] = bv.x;
        Bs[col4 + 1][row64] = bv.y;
        Bs[col4 + 2][row64] = bv.z;
        Bs[col4 + 3][row64] = bv.w;
        __syncthreads();
#pragma unroll
        for (int kk = 0; kk < BK; kk++) {
            const float4 a = *(const float4*)&As[kk][ty * 4];
            const float4 b = *(const float4*)&Bs[kk][tx * 4];
            acc[0][0] += a.x * b.x; acc[0][1] += a.x * b.y; acc[0][2] += a.x * b.z; acc[0][3] += a.x * b.w;
            acc[1][0] += a.y * b.x; acc[1][1] += a.y * b.y; acc[1][2] += a.y * b.z; acc[1][3] += a.y * b.w;
            acc[2][0] += a.z * b.x; acc[2][1] += a.z * b.y; acc[2][2] += a.z * b.z; acc[2][3] += a.z * b.w;
            acc[3][0] += a.w * b.x; acc[3][1] += a.w * b.y; acc[3][2] += a.w * b.z; acc[3][3] += a.w * b.w;
        }
    }

    const int mbase = m0 + ty * 4, nbase = nOff + n0 + tx * 4;
#pragma unroll
    for (int ii = 0; ii < 4; ii++)
        *(float4*)&Srow[(size_t)(mbase + ii) * SN + nbase] =
            make_float4(acc[ii][0], acc[ii][1], acc[ii][2], acc[ii][3]);
}

// -------- softmax over S rows: P[j] = softmax_j((AC[j] + Srel[j+255-i]) * scale), in place --------
__global__ __launch_bounds__(256) void softmax_kernel(float* __restrict__ S)
{
    const int r = blockIdx.x * 4 + (threadIdx.x >> 6);  // chunk-local row id
    const int lane = threadIdx.x & 63;
    const int i = r & (QLEN - 1);
    float* sRow = S + (size_t)r * SN;
    const int off = (QLEN - 1) - i;

    float v[8];
#pragma unroll
    for (int u = 0; u < 8; u++) {
        const int j = u * 64 + lane;
        const bool valid = (j <= i + MLEN);
        v[u] = valid ? (sRow[j] + sRow[512 + j + off]) * SCALE : -1e30f;
    }
    float m = v[0];
#pragma unroll
    for (int u = 1; u < 8; u++) m = fmaxf(m, v[u]);
#pragma unroll
    for (int d = 32; d > 0; d >>= 1) m = fmaxf(m, __shfl_xor(m, d, 64));
    float s = 0.f;
#pragma unroll
    for (int u = 0; u < 8; u++) { v[u] = __expf(v[u] - m); s += v[u]; }
#pragma unroll
    for (int d = 32; d > 0; d >>= 1) s += __shfl_xor(s, d, 64);
    const float inv = 1.f / s;
#pragma unroll
    for (int u = 0; u < 8; u++) sRow[u * 64 + lane] = v[u] * inv;
}

// -------- batched PV GEMM (NN): vec[i][b][n*64+d] = sum_j P[bn][i][j] * V[bn][j][d] --------
__global__ __launch_bounds__(256) void pv_gemm(
    const float* __restrict__ S, const float* __restrict__ Vbase,
    float* __restrict__ vec, int bnBase)
{
    __shared__ float As[BK][BM + 4];
    __shared__ float Bs[BK][BN + 4];

    const int bnLoc = blockIdx.z;
    const int bn = bnBase + bnLoc;
    const float* P = S + (size_t)bnLoc * QLEN * SN;
    const float* V = Vbase + (size_t)bn * KLEN * DH;

    const int tid = threadIdx.x;
    const int tx = tid & 15, ty = tid >> 4;
    const int m0 = blockIdx.y * BM;   // n0 = 0 (N = 64)

    float acc[4][4] = {};
    const int arow = tid >> 2;
    const int acol = (tid & 3) * 4;
    const int brow = tid >> 4;
    const int bcol = (tid & 15) * 4;

    for (int k0 = 0; k0 < KLEN; k0 += BK) {
        const float4 av = *(const float4*)(P + (size_t)(m0 + arow) * SN + k0 + acol);
        const float4 bv = *(const float4*)(V + (size_t)(k0 + brow) * DH + bcol);
        __syncthreads();
        As[acol + 0][arow] = av.x;
        As[acol + 1][arow] = av.y;
        As[acol + 2][arow] = av.z;
        As[acol + 3][arow] = av.w;
        *(float4*)&Bs[brow][bcol] = bv;
        __syncthreads();
#pragma unroll
        for (int kk = 0; kk < BK; kk++) {
            const float4 a = *(const float4*)&As[kk][ty * 4];
            const float4 b = *(const float4*)&Bs[kk][tx * 4];
            acc[0][0] += a.x * b.x; acc[0][1] += a.x * b.y; acc[0][2] += a.x * b.z; acc[0][3] += a.x * b.w;
            acc[1][0] += a.y * b.x; acc[1][1] += a.y * b.y; acc[1][2] += a.y * b.z; acc[1][3] += a.y * b.w;
            acc[2][0] += a.z * b.x; acc[2][1] += a.z * b.y; acc[2][2] += a.z * b.z; acc[2][3] += a.z * b.w;
            acc[3][0] += a.w * b.x; acc[3][1] += a.w * b.y; acc[3][2] += a.w * b.z; acc[3][3] += a.w * b.w;
        }
    }

    const int b_ = bn >> 3, n = bn & 7;
    const int mbase = m0 + ty * 4, nbase = tx * 4;
#pragma unroll
    for (int ii = 0; ii < 4; ii++) {
        const int i = mbase + ii;
        float* out = vec + ((size_t)i * BSZ + b_) * (H * DH) + n * DH + nbase;
        *(float4*)out = make_float4(acc[ii][0], acc[ii][1], acc[ii][2], acc[ii][3]);
    }
}

// ---------------- fused residual + LayerNorm (in place on h) ----------------
__global__ __launch_bounds__(256) void ln_kernel(
    float* __restrict__ h, const float* __restrict__ add,
    const float* __restrict__ g, const float* __restrict__ b)
{
    const int row = blockIdx.x;
    const int t = threadIdx.x;
    const size_t base = (size_t)row * DM;
    const float x0 = h[base + t] + add[base + t];
    const float x1 = h[base + t + 256] + add[base + t + 256];
    float s = x0 + x1;
    float s2 = x0 * x0 + x1 * x1;
#pragma unroll
    for (int off = 32; off > 0; off >>= 1) {
        s += __shfl_down(s, off, 64);
        s2 += __shfl_down(s2, off, 64);
    }
    __shared__ float ws1[4], ws2[4];
    const int wid = t >> 6, lane = t & 63;
    if (lane == 0) { ws1[wid] = s; ws2[wid] = s2; }
    __syncthreads();
    __shared__ float mv[2];
    if (t == 0) {
        float a = 0.f, a2 = 0.f;
        for (int w = 0; w < 4; w++) { a += ws1[w]; a2 += ws2[w]; }
        const float mean = a / (float)DM;
        mv[0] = mean;
        mv[1] = rsqrtf(a2 / (float)DM - mean * mean + EPS);
    }
    __syncthreads();
    const float mean = mv[0], rstd = mv[1];
    h[base + t] = (x0 - mean) * rstd * g[t] + b[t];
    h[base + t + 256] = (x1 - mean) * rstd * g[t + 256] + b[t + 256];
}

// ---------------- launcher ----------------
extern "C" void kernel_launch(void* const* d_in, const int* in_sizes, int n_in,
                              void* d_out, int out_size, void* d_ws, size_t ws_size,
                              hipStream_t stream)
{
    const float* w      = (const float*)d_in[0];
    const float* mems   = (const float*)d_in[1];
    const float* qkv_w  = (const float*)d_in[2];
    const float* rnet_w = (const float*)d_in[3];
    const float* o_w    = (const float*)d_in[4];
    const float* ln1_g  = (const float*)d_in[5];
    const float* ln1_b  = (const float*)d_in[6];
    const float* ff_w1  = (const float*)d_in[7];
    const float* ff_b1  = (const float*)d_in[8];
    const float* ff_w2  = (const float*)d_in[9];
    const float* ff_b2  = (const float*)d_in[10];
    const float* ln2_g  = (const float*)d_in[11];
    const float* ln2_b  = (const float*)d_in[12];
    const float* rwb    = (const float*)d_in[13];
    const float* rrb    = (const float*)d_in[14];

    // workspace layout (floats)
    float* hbuf  = (float*)d_ws;                        // 4,194,304
    float* rbuf  = hbuf  + (size_t)QLEN * BSZ * DM;     //   262,144
    float* qwbuf = rbuf  + (size_t)KLEN * DM;           // 4,194,304
    float* qrbuf = qwbuf + (size_t)BSZ * H * QLEN * DH; // 4,194,304
    float* kbuf  = qrbuf + (size_t)BSZ * H * QLEN * DH; // 8,388,608
    float* vbuf  = kbuf  + (size_t)BSZ * H * KLEN * DH; // 8,388,608
    float* rkbuf = vbuf  + (size_t)BSZ * H * KLEN * DH; //   262,144
    float* vecb  = rkbuf + (size_t)H * KLEN * DH;       // 4,194,304
    float* sbuf  = vecb  + (size_t)QLEN * BSZ * DM;     // CH*256*1024
    float* atmp  = qwbuf;   // alias (qw dead after score GEMMs)
    float* ff1   = kbuf;    // alias (spans kbuf+vbuf)
    float* ff2t  = vecb;    // alias

    const size_t fixedFloats = (size_t)(sbuf - hbuf);
    const size_t availFloats = ws_size / 4 - fixedFloats;
    int CH = 256;
    while (CH > 8 && (size_t)CH * QLEN * SN > availFloats) CH >>= 1;

    hipMemcpyAsync(hbuf, w, (size_t)QLEN * BSZ * DM * sizeof(float),
                   hipMemcpyDeviceToDevice, stream);
    r_kernel<<<(KLEN * DM) / 256, 256, 0, stream>>>(rbuf);

    const int BIG = 1 << 30;
    for (int l = 0; l < LNUM; l++) {
        // QKV: concat(mems[l], h) @ qkv_w, scatter epilogue (q gets biases folded)
        gemm_kernel<<<dim3((3 * H * DH) / BN, (KLEN * BSZ) / BM), 256, 0, stream>>>(
            mems + (size_t)l * MLEN * BSZ * DM, hbuf, MLEN * BSZ,
            qkv_w + (size_t)l * DM * 3 * H * DH, nullptr,
            KLEN * BSZ, 3 * H * DH, DM, EP_QKV, nullptr,
            qwbuf, qrbuf, kbuf, vbuf, rwb, rrb);
        // r_head_k: r @ r_net_w, scatter to rk[H][KLEN][DH]
        gemm_kernel<<<dim3((H * DH) / BN, KLEN / BM), 256, 0, stream>>>(
            rbuf, rbuf, BIG, rnet_w + (size_t)l * DM * H * DH, rkbuf,
            KLEN, H * DH, DM, EP_RK, nullptr,
            nullptr, nullptr, nullptr, nullptr, nullptr, nullptr);
        // attention, chunked over bn
        for (int bn0 = 0; bn0 < BSZ * H; bn0 += CH) {
            score_gemm<<<dim3(KLEN / BN, QLEN / BM, CH), 256, 0, stream>>>(
                qwbuf, kbuf, 0, sbuf, 0, bn0);
            score_gemm<<<dim3(KLEN / BN, QLEN / BM, CH), 256, 0, stream>>>(
                qrbuf, rkbuf, 1, sbuf, 512, bn0);
            softmax_kernel<<<(CH * QLEN) / 4, 256, 0, stream>>>(sbuf);
            pv_gemm<<<dim3(1, QLEN / BM, CH), 256, 0, stream>>>(sbuf, vbuf, vecb, bn0);
        }
        // O projection
        gemm_kernel<<<dim3(DM / BN, (QLEN * BSZ) / BM), 256, 0, stream>>>(
            vecb, vecb, BIG, o_w + (size_t)l * H * DH * DM, atmp,
            QLEN * BSZ, DM, H * DH, EP_PLAIN, nullptr,
            nullptr, nullptr, nullptr, nullptr, nullptr, nullptr);
        ln_kernel<<<QLEN * BSZ, 256, 0, stream>>>(hbuf, atmp, ln1_g + l * DM, ln1_b + l * DM);
        // FF1 (+bias+relu)
        gemm_kernel<<<dim3(DI / BN, (QLEN * BSZ) / BM), 256, 0, stream>>>(
            hbuf, hbuf, BIG, ff_w1 + (size_t)l * DM * DI, ff1,
            QLEN * BSZ, DI, DM, EP_BIAS_RELU, ff_b1 + (size_t)l * DI,
            nullptr, nullptr, nullptr, nullptr, nullptr, nullptr);
        // FF2 (+bias)
        gemm_kernel<<<dim3(DM / BN, (QLEN * BSZ) / BM), 256, 0, stream>>>(
            ff1, ff1, BIG, ff_w2 + (size_t)l * DI * DM, ff2t,
            QLEN * BSZ, DM, DI, EP_BIAS, ff_b2 + (size_t)l * DM,
            nullptr, nullptr, nullptr, nullptr, nullptr, nullptr);
        ln_kernel<<<QLEN * BSZ, 256, 0, stream>>>(hbuf, ff2t, ln2_g + l * DM, ln2_b + l * DM);
    }
    hipMemcpyAsync(d_out, hbuf, (size_t)out_size * sizeof(float),
                   hipMemcpyDeviceToDevice, stream);
}

// Round 3
// 2502.686 us; speedup vs baseline: 4.4378x; 2.9374x over previous
//
#include <hip/hip_runtime.h>
#include <math.h>

#define LNUM 6
#define H 8
#define DM 512
#define DH 64
#define DI 2048
#define QLEN 256
#define BSZ 32
#define MLEN 256
#define KLEN (QLEN + MLEN)   // 512
#define EPS 1e-5f
#define SCALE 0.125f
#define SN 1024              // S row: [AC(512) | Srel(512)] bf16

typedef unsigned short u16;
typedef short bf16x8 __attribute__((ext_vector_type(8)));
typedef float f32x4 __attribute__((ext_vector_type(4)));

__device__ __forceinline__ u16 f2b(float f) {
    union { float f; unsigned u; } x; x.f = f;
    const unsigned r = x.u + 0x7FFFu + ((x.u >> 16) & 1u);
    return (u16)(r >> 16);
}
__device__ __forceinline__ float b2f(u16 b) {
    union { unsigned u; float f; } x; x.u = (unsigned)b << 16;
    return x.f;
}

// ================= bf16 MFMA GEMM: C[M,N] = A[M,K] @ Bt[N,K]^T =================
// 128 x TBN tile, BK=32, 256 threads (4 waves, each 64 x TBN/2).
// EPIL: 0 f32, 1 f32+bias, 2 bf16 relu+bias, 3 QKV scatter, 4 RK scatter,
//       5 score (AC z<CHp / Srel z>=CHp) -> bf16 S, 6 PV -> bf16 vec scatter
template<int TBN, int EPIL>
__global__ __launch_bounds__(256) void mm_bt(
    const u16* __restrict__ A0, const u16* __restrict__ A1, int split,
    const u16* __restrict__ Bt, const u16* __restrict__ Bt2,
    int M, int N, int K,
    long aBatch, long bBatch, int bMask,
    float* __restrict__ Cf, u16* __restrict__ Cb,
    const float* __restrict__ bias,
    u16* __restrict__ o2, u16* __restrict__ o3, u16* __restrict__ o4,
    const float* __restrict__ rwb, const float* __restrict__ rrb,
    int bnBase, int CHp)
{
    constexpr int NT = (TBN == 128) ? 4 : 2;
    __shared__ u16 Al[128 * 40];
    __shared__ u16 Bl[TBN * 40];

    const int tid = threadIdx.x;
    const int w = tid >> 6, lane = tid & 63;
    const int lr = tid >> 2, lc = (tid & 3) * 8;
    const int m0 = blockIdx.y * 128;
    const int n0 = blockIdx.x * TBN;

    int z = blockIdx.z;
    int nOff = 0;
    const u16* Ab; const u16* Ab1; const u16* Bb;
    if constexpr (EPIL == 5) {
        const bool rel = (z >= CHp);
        if (rel) { z -= CHp; nOff = 512; }
        Ab = (rel ? A1 : A0) + (size_t)z * aBatch;
        Ab1 = Ab;
        Bb = rel ? (Bt2 + (size_t)(z & 7) * bBatch)
                 : (Bt + (size_t)z * bBatch);
    } else {
        Ab = A0 + (size_t)z * aBatch;
        Ab1 = A1 + (size_t)z * aBatch;
        Bb = Bt + (size_t)(z & bMask) * bBatch;
    }

    const int gm1 = m0 + lr, gm2 = m0 + 64 + lr;
    const u16* ap1 = ((gm1 < split) ? Ab + (size_t)gm1 * K
                                    : Ab1 + (size_t)(gm1 - split) * K) + lc;
    const u16* ap2 = ((gm2 < split) ? Ab + (size_t)gm2 * K
                                    : Ab1 + (size_t)(gm2 - split) * K) + lc;
    const u16* bp1 = Bb + (size_t)(n0 + lr) * K + lc;
    const u16* bp2 = (TBN == 128) ? Bb + (size_t)(n0 + 64 + lr) * K + lc : nullptr;

    const int wm = (w >> 1) * 64, wn = (w & 1) * (TBN / 2);
    const int fr = lane & 15, fq = (lane >> 4) * 8;

    f32x4 acc[4][NT] = {};

    for (int k0 = 0; k0 < K; k0 += 32) {
        const uint4 av1 = *(const uint4*)(ap1 + k0);
        const uint4 av2 = *(const uint4*)(ap2 + k0);
        const uint4 bv1 = *(const uint4*)(bp1 + k0);
        uint4 bv2;
        if constexpr (TBN == 128) bv2 = *(const uint4*)(bp2 + k0);
        __syncthreads();
        *(uint4*)&Al[lr * 40 + lc] = av1;
        *(uint4*)&Al[(64 + lr) * 40 + lc] = av2;
        *(uint4*)&Bl[lr * 40 + lc] = bv1;
        if constexpr (TBN == 128) *(uint4*)&Bl[(64 + lr) * 40 + lc] = bv2;
        __syncthreads();

        bf16x8 af[4], bfr[NT];
#pragma unroll
        for (int mt = 0; mt < 4; mt++)
            af[mt] = *(const bf16x8*)&Al[(wm + mt * 16 + fr) * 40 + fq];
#pragma unroll
        for (int nt = 0; nt < NT; nt++)
            bfr[nt] = *(const bf16x8*)&Bl[(wn + nt * 16 + fr) * 40 + fq];
#pragma unroll
        for (int mt = 0; mt < 4; mt++)
#pragma unroll
            for (int nt = 0; nt < NT; nt++)
                acc[mt][nt] = __builtin_amdgcn_mfma_f32_16x16x32_bf16(
                    af[mt], bfr[nt], acc[mt][nt], 0, 0, 0);
    }

    const int col = lane & 15, quad = lane >> 4;
#pragma unroll
    for (int mt = 0; mt < 4; mt++)
#pragma unroll
    for (int nt = 0; nt < NT; nt++)
#pragma unroll
    for (int r = 0; r < 4; r++) {
        const int m = m0 + wm + mt * 16 + quad * 4 + r;
        const int n = n0 + wn + nt * 16 + col;
        const float v = acc[mt][nt][r];
        if constexpr (EPIL == 0) {
            Cf[(size_t)m * N + n] = v;
        } else if constexpr (EPIL == 1) {
            Cf[(size_t)m * N + n] = v + bias[n];
        } else if constexpr (EPIL == 2) {
            Cb[(size_t)m * N + n] = f2b(fmaxf(v + bias[n], 0.f));
        } else if constexpr (EPIL == 3) {
            const int kl = m >> 5, b_ = m & 31;
            const int sec = n >> 9, cc = n & 511, hd = cc >> 6, dd = cc & 63;
            const int bh = b_ * H + hd;
            if (sec == 1) o3[((size_t)bh * KLEN + kl) * DH + dd] = f2b(v);
            else if (sec == 2) o4[((size_t)bh * DH + dd) * KLEN + kl] = f2b(v);
            else if (kl >= MLEN) {
                const size_t qi = ((size_t)bh * QLEN + (kl - MLEN)) * DH + dd;
                Cb[qi] = f2b(v + rwb[hd * DH + dd]);
                o2[qi] = f2b(v + rrb[hd * DH + dd]);
            }
        } else if constexpr (EPIL == 4) {
            const int hd = n >> 6, dd = n & 63;
            Cb[(size_t)hd * KLEN * DH + (size_t)m * DH + dd] = f2b(v);
        } else if constexpr (EPIL == 5) {
            Cb[(size_t)z * QLEN * SN + (size_t)m * SN + nOff + n] = f2b(v);
        } else if constexpr (EPIL == 6) {
            const int bn = bnBase + z;
            const int b_ = bn >> 3, nh = bn & 7;
            Cb[((size_t)m * BSZ + b_) * (H * DH) + nh * DH + n] = f2b(v);
        }
    }
}

// ---------- fused 5-weight transpose fp32[K][N] -> bf16[N][K], one launch ----------
__global__ __launch_bounds__(256) void tr5_kernel(
    const float* __restrict__ s0, const float* __restrict__ s1,
    const float* __restrict__ s2, const float* __restrict__ s3,
    const float* __restrict__ s4,
    u16* __restrict__ d0, u16* __restrict__ d1, u16* __restrict__ d2,
    u16* __restrict__ d3, u16* __restrict__ d4)
{
    const float* src; u16* dst; int K, N;
    switch (blockIdx.z) {
        case 0: src = s0; dst = d0; K = 512;  N = 1536; break;
        case 1: src = s1; dst = d1; K = 512;  N = 512;  break;
        case 2: src = s2; dst = d2; K = 512;  N = 512;  break;
        case 3: src = s3; dst = d3; K = 512;  N = 2048; break;
        default: src = s4; dst = d4; K = 2048; N = 512; break;
    }
    const int n0 = blockIdx.x * 32, k0 = blockIdx.y * 32;
    if (n0 >= N || k0 >= K) return;
    const int tx = threadIdx.x & 31, ty = threadIdx.x >> 5;
    __shared__ float t[32][33];
#pragma unroll
    for (int r = 0; r < 4; r++)
        t[ty + r * 8][tx] = src[(size_t)(k0 + ty + r * 8) * N + n0 + tx];
    __syncthreads();
#pragma unroll
    for (int r = 0; r < 4; r++)
        dst[(size_t)(n0 + ty + r * 8) * K + k0 + tx] = f2b(t[tx][ty + r * 8]);
}

// ---------- fp32 -> bf16 elementwise (x4) ----------
__global__ __launch_bounds__(256) void cvt4_kernel(const float* __restrict__ s,
                                                   u16* __restrict__ d)
{
    const int i = blockIdx.x * 256 + threadIdx.x;
    const float4 v = ((const float4*)s)[i];
    ((ushort4*)d)[i] = make_ushort4(f2b(v.x), f2b(v.y), f2b(v.z), f2b(v.w));
}

// ---------- copy fp32 + make bf16 copy ----------
__global__ __launch_bounds__(256) void copyh_kernel(const float* __restrict__ s,
                                                    float* __restrict__ h,
                                                    u16* __restrict__ hb)
{
    const int i = blockIdx.x * 256 + threadIdx.x;
    const float4 v = ((const float4*)s)[i];
    ((float4*)h)[i] = v;
    ((ushort4*)hb)[i] = make_ushort4(f2b(v.x), f2b(v.y), f2b(v.z), f2b(v.w));
}

// ---------- positional embedding r[KLEN][DM] bf16 ----------
__global__ __launch_bounds__(256) void r_kernel(u16* __restrict__ rb)
{
    const int idx = blockIdx.x * 256 + threadIdx.x;
    const int p = idx >> 9, c = idx & 511;
    const float pos = (float)(KLEN - 1 - p);
    const int i2 = (c < 256) ? c : (c - 256);
    const float invf = expf(-((float)(2 * i2) / (float)DM) * logf(10000.0f));
    const float a = pos * invf;
    rb[idx] = f2b((c < 256) ? sinf(a) : cosf(a));
}

// ---------- softmax: P = softmax((AC + shifted Srel)*scale), bf16 in/out ----------
__global__ __launch_bounds__(256) void softmax_kernel(const u16* __restrict__ S,
                                                      u16* __restrict__ P)
{
    const int r = blockIdx.x * 4 + (threadIdx.x >> 6);
    const int lane = threadIdx.x & 63;
    const int i = r & (QLEN - 1);
    const u16* sRow = S + (size_t)r * SN;
    u16* pRow = P + (size_t)r * KLEN;
    const int off = (QLEN - 1) - i;

    float v[8];
#pragma unroll
    for (int u = 0; u < 8; u++) {
        const int j = u * 64 + lane;
        v[u] = (j <= i + MLEN)
             ? (b2f(sRow[j]) + b2f(sRow[512 + j + off])) * SCALE : -1e30f;
    }
    float m = v[0];
#pragma unroll
    for (int u = 1; u < 8; u++) m = fmaxf(m, v[u]);
#pragma unroll
    for (int d = 32; d > 0; d >>= 1) m = fmaxf(m, __shfl_xor(m, d, 64));
    float s = 0.f;
#pragma unroll
    for (int u = 0; u < 8; u++) { v[u] = __expf(v[u] - m); s += v[u]; }
#pragma unroll
    for (int d = 32; d > 0; d >>= 1) s += __shfl_xor(s, d, 64);
    const float inv = 1.f / s;
#pragma unroll
    for (int u = 0; u < 8; u++) pRow[u * 64 + lane] = f2b(v[u] * inv);
}

// ---------- fused residual + LayerNorm, writes fp32 h and bf16 hb ----------
__global__ __launch_bounds__(256) void ln_kernel(
    float* __restrict__ h, u16* __restrict__ hb, const float* __restrict__ add,
    const float* __restrict__ g, const float* __restrict__ b)
{
    const int row = blockIdx.x;
    const int t = threadIdx.x;
    const size_t base = (size_t)row * DM;
    const float x0 = h[base + t] + add[base + t];
    const float x1 = h[base + t + 256] + add[base + t + 256];
    float s = x0 + x1;
    float s2 = x0 * x0 + x1 * x1;
#pragma unroll
    for (int off = 32; off > 0; off >>= 1) {
        s += __shfl_down(s, off, 64);
        s2 += __shfl_down(s2, off, 64);
    }
    __shared__ float ws1[4], ws2[4];
    const int wid = t >> 6, lane = t & 63;
    if (lane == 0) { ws1[wid] = s; ws2[wid] = s2; }
    __syncthreads();
    __shared__ float mv[2];
    if (t == 0) {
        float a = 0.f, a2 = 0.f;
        for (int wv = 0; wv < 4; wv++) { a += ws1[wv]; a2 += ws2[wv]; }
        const float mean = a / (float)DM;
        mv[0] = mean;
        mv[1] = rsqrtf(a2 / (float)DM - mean * mean + EPS);
    }
    __syncthreads();
    const float mean = mv[0], rstd = mv[1];
    const float r0 = (x0 - mean) * rstd * g[t] + b[t];
    const float r1 = (x1 - mean) * rstd * g[t + 256] + b[t + 256];
    h[base + t] = r0;
    h[base + t + 256] = r1;
    hb[base + t] = f2b(r0);
    hb[base + t + 256] = f2b(r1);
}

// ---------------- launcher ----------------
extern "C" void kernel_launch(void* const* d_in, const int* in_sizes, int n_in,
                              void* d_out, int out_size, void* d_ws, size_t ws_size,
                              hipStream_t stream)
{
    const float* w      = (const float*)d_in[0];
    const float* mems   = (const float*)d_in[1];
    const float* qkv_w  = (const float*)d_in[2];
    const float* rnet_w = (const float*)d_in[3];
    const float* o_w    = (const float*)d_in[4];
    const float* ln1_g  = (const float*)d_in[5];
    const float* ln1_b  = (const float*)d_in[6];
    const float* ff_w1  = (const float*)d_in[7];
    const float* ff_b1  = (const float*)d_in[8];
    const float* ff_w2  = (const float*)d_in[9];
    const float* ff_b2  = (const float*)d_in[10];
    const float* ln2_g  = (const float*)d_in[11];
    const float* ln2_b  = (const float*)d_in[12];
    const float* rwb    = (const float*)d_in[13];
    const float* rrb    = (const float*)d_in[14];

    char* p = (char*)d_ws;
    auto alloc = [&](size_t bytes) { void* r = p; p += (bytes + 255) & ~(size_t)255; return r; };

    float* hbuf  = (float*)alloc((size_t)QLEN * BSZ * DM * 4);
    u16*   hb    = (u16*)alloc((size_t)QLEN * BSZ * DM * 2);
    u16*   rb    = (u16*)alloc((size_t)KLEN * DM * 2);
    u16*   memsb = (u16*)alloc((size_t)MLEN * BSZ * DM * 2);
    u16*   qkvwt = (u16*)alloc((size_t)DM * 3 * H * DH * 2);
    u16*   rkwt  = (u16*)alloc((size_t)DM * H * DH * 2);
    u16*   owt   = (u16*)alloc((size_t)H * DH * DM * 2);
    u16*   f1wt  = (u16*)alloc((size_t)DM * DI * 2);
    u16*   f2wt  = (u16*)alloc((size_t)DI * DM * 2);
    u16*   rkb   = (u16*)alloc((size_t)H * KLEN * DH * 2);
    u16*   vecb  = (u16*)alloc((size_t)QLEN * BSZ * DM * 2);
    char*  R1    = (char*)alloc((size_t)QLEN * BSZ * DM * 4);       // 16.8 MB
    char*  R2    = (char*)alloc((size_t)BSZ * H * KLEN * DH * 4);   // 33.6 MB
    u16*   qwb = (u16*)R1;
    u16*   qrb = (u16*)(R1 + (size_t)BSZ * H * QLEN * DH * 2);
    float* atmp = (float*)R1;     // alias: live after scores are consumed
    float* ff2t = (float*)R1;     // alias: live after atmp is consumed
    u16*   kb  = (u16*)R2;
    u16*   vtb = (u16*)(R2 + (size_t)BSZ * H * KLEN * DH * 2);
    u16*   ff1b = (u16*)R2;       // alias: live after attention done

    const size_t used = (size_t)(p - (char*)d_ws);
    const size_t avail = ws_size > used ? ws_size - used : 0;
    int CH = 64;
    while (CH > 8 && (size_t)CH * ((size_t)QLEN * SN * 2 + (size_t)QLEN * KLEN * 2) > avail)
        CH >>= 1;
    u16* sbuf = (u16*)alloc((size_t)CH * QLEN * SN * 2);
    u16* pbuf = (u16*)alloc((size_t)CH * QLEN * KLEN * 2);

    const int BIG = 1 << 30;
    const int HD = H * DH;   // 512

    copyh_kernel<<<(QLEN * BSZ * DM) / 1024, 256, 0, stream>>>(w, hbuf, hb);
    r_kernel<<<(KLEN * DM) / 256, 256, 0, stream>>>(rb);

    for (int l = 0; l < LNUM; l++) {
        cvt4_kernel<<<(MLEN * BSZ * DM) / 1024, 256, 0, stream>>>(
            mems + (size_t)l * MLEN * BSZ * DM, memsb);
        tr5_kernel<<<dim3(64, 64, 5), 256, 0, stream>>>(
            qkv_w + (size_t)l * DM * 3 * HD, rnet_w + (size_t)l * DM * HD,
            o_w + (size_t)l * HD * DM, ff_w1 + (size_t)l * DM * DI,
            ff_w2 + (size_t)l * DI * DM,
            qkvwt, rkwt, owt, f1wt, f2wt);

        // QKV with scatter epilogue
        mm_bt<128, 3><<<dim3(12, 128, 1), 256, 0, stream>>>(
            memsb, hb, MLEN * BSZ, qkvwt, nullptr,
            KLEN * BSZ, 3 * HD, DM, 0, 0, 0,
            nullptr, qwb, nullptr, qrb, kb, vtb, rwb, rrb, 0, 0);
        // r_head_k
        mm_bt<128, 4><<<dim3(4, 4, 1), 256, 0, stream>>>(
            rb, rb, BIG, rkwt, nullptr,
            KLEN, HD, DM, 0, 0, 0,
            nullptr, rkb, nullptr, nullptr, nullptr, nullptr, nullptr, nullptr, 0, 0);

        for (int bn0 = 0; bn0 < BSZ * H; bn0 += CH) {
            // AC (z<CH) and Srel (z>=CH) in one launch
            mm_bt<128, 5><<<dim3(4, 2, 2 * CH), 256, 0, stream>>>(
                qwb + (size_t)bn0 * QLEN * DH, qrb + (size_t)bn0 * QLEN * DH, BIG,
                kb + (size_t)bn0 * KLEN * DH, rkb,
                QLEN, KLEN, DH, (long)QLEN * DH, (long)KLEN * DH, 0,
                nullptr, sbuf, nullptr, nullptr, nullptr, nullptr,
                nullptr, nullptr, bn0, CH);
            softmax_kernel<<<CH * 64, 256, 0, stream>>>(sbuf, pbuf);
            mm_bt<64, 6><<<dim3(1, 2, CH), 256, 0, stream>>>(
                pbuf, pbuf, BIG, vtb + (size_t)bn0 * DH * KLEN, nullptr,
                QLEN, DH, KLEN, (long)QLEN * KLEN, (long)DH * KLEN, 0x7FFFFFFF,
                nullptr, vecb, nullptr, nullptr, nullptr, nullptr,
                nullptr, nullptr, bn0, 0);
        }

        // O projection -> fp32 atmp
        mm_bt<128, 0><<<dim3(4, 64, 1), 256, 0, stream>>>(
            vecb, vecb, BIG, owt, nullptr,
            QLEN * BSZ, DM, HD, 0, 0, 0,
            atmp, nullptr, nullptr, nullptr, nullptr, nullptr, nullptr, nullptr, 0, 0);
        ln_kernel<<<QLEN * BSZ, 256, 0, stream>>>(hbuf, hb, atmp,
                                                  ln1_g + l * DM, ln1_b + l * DM);
        // FF1 (+bias+relu) -> bf16
        mm_bt<128, 2><<<dim3(16, 64, 1), 256, 0, stream>>>(
            hb, hb, BIG, f1wt, nullptr,
            QLEN * BSZ, DI, DM, 0, 0, 0,
            nullptr, ff1b, ff_b1 + (size_t)l * DI, nullptr, nullptr, nullptr,
            nullptr, nullptr, 0, 0);
        // FF2 (+bias) -> fp32
        mm_bt<128, 1><<<dim3(4, 64, 1), 256, 0, stream>>>(
            ff1b, ff1b, BIG, f2wt, nullptr,
            QLEN * BSZ, DM, DI, 0, 0, 0,
            ff2t, nullptr, ff_b2 + (size_t)l * DM, nullptr, nullptr, nullptr,
            nullptr, nullptr, 0, 0);
        ln_kernel<<<QLEN * BSZ, 256, 0, stream>>>(hbuf, hb, ff2t,
                                                  ln2_g + l * DM, ln2_b + l * DM);
    }
    hipMemcpyAsync(d_out, hbuf, (size_t)out_size * sizeof(float),
                   hipMemcpyDeviceToDevice, stream);
}

// Round 5
// 2234.350 us; speedup vs baseline: 4.9708x; 1.1201x over previous
//
#include <hip/hip_runtime.h>
#include <math.h>

#define LNUM 6
#define H 8
#define DM 512
#define DH 64
#define DI 2048
#define QLEN 256
#define BSZ 32
#define MLEN 256
#define KLEN (QLEN + MLEN)   // 512
#define EPS 1e-5f
#define SCALE 0.125f
#define SN 1024              // S row: [AC(512) | Srel(512)] bf16

typedef unsigned short u16;
typedef short bf16x8 __attribute__((ext_vector_type(8)));
typedef float f32x4 __attribute__((ext_vector_type(4)));

__device__ __forceinline__ u16 f2b(float f) {
    union { float f; unsigned u; } x; x.f = f;
    const unsigned r = x.u + 0x7FFFu + ((x.u >> 16) & 1u);
    return (u16)(r >> 16);
}
__device__ __forceinline__ float b2f(u16 b) {
    union { unsigned u; float f; } x; x.u = (unsigned)b << 16;
    return x.f;
}

// async 16B global -> LDS (wave-uniform base + lane*16; &lds[tid*8] satisfies it)
__device__ __forceinline__ void gl16(const u16* g, u16* l) {
    __builtin_amdgcn_global_load_lds(
        (const __attribute__((address_space(1))) unsigned int*)g,
        (__attribute__((address_space(3))) unsigned int*)l, 16, 0, 0);
}

// ================= bf16 MFMA GEMM: C[M,N] = A[M,K] @ Bt[N,K]^T =================
// 128 x TBN tile, BK=32, 256 threads (4 waves). global_load_lds staging with
// XOR chunk swizzle: LDS chunk t holds global (row t>>2, col (t&3)^swz(row)),
// swz(r) = (r&3)^((r>>2)&1) -> fragment ds_read_b128 is 2-way max (free).
// EPIL: 0 f32, 1 f32+bias, 2 bf16 relu+bias, 3 QKV scatter, 4 RK scatter (batched),
//       5 score (AC z<CHp / Srel z>=CHp) -> bf16 S, 6 PV -> bf16 vec scatter
template<int TBN, int EPIL>
__global__ __launch_bounds__(256) void mm_bt(
    const u16* __restrict__ A0, const u16* __restrict__ A1, int split,
    const u16* __restrict__ Bt, const u16* __restrict__ Bt2,
    int M, int N, int K,
    long aBatch, long bBatch, int bMask,
    float* __restrict__ Cf, u16* __restrict__ Cb,
    const float* __restrict__ bias,
    u16* __restrict__ o2, u16* __restrict__ o3, u16* __restrict__ o4,
    const float* __restrict__ rwb, const float* __restrict__ rrb,
    int bnBase, int CHp)
{
    constexpr int NT = (TBN == 128) ? 4 : 2;
    __shared__ u16 lds[(128 + TBN) * 32];   // A: 128x64B, B: TBNx64B

    const int tid = threadIdx.x;
    const int w = tid >> 6, lane = tid & 63;
    const int m0 = blockIdx.y * 128;
    const int n0 = blockIdx.x * TBN;

    int z = blockIdx.z;
    int nOff = 0;
    const u16* Ab; const u16* Ab1; const u16* Bb;
    if constexpr (EPIL == 5) {
        const bool rel = (z >= CHp);
        if (rel) { z -= CHp; nOff = 512; }
        Ab = (rel ? A1 : A0) + (size_t)z * aBatch;
        Ab1 = Ab;
        Bb = rel ? (Bt2 + (size_t)(z & 7) * bBatch)
                 : (Bt + (size_t)z * bBatch);
    } else {
        Ab = A0 + (size_t)z * aBatch;
        Ab1 = A1 + (size_t)z * aBatch;
        Bb = Bt + (size_t)(z & bMask) * bBatch;
    }

    // staging: thread t loads global chunk (row t>>2, col (t&3)^swz(row))
    const int rt = tid >> 2;
    const int ct = (tid & 3) ^ (rt & 3) ^ ((rt >> 2) & 1);
    const int cofs = ct * 8;   // u16 elements

    const int gm1 = m0 + rt, gm2 = m0 + 64 + rt;
    const u16* ap1 = ((gm1 < split) ? Ab + (size_t)gm1 * K
                                    : Ab1 + (size_t)(gm1 - split) * K) + cofs;
    const u16* ap2 = ((gm2 < split) ? Ab + (size_t)gm2 * K
                                    : Ab1 + (size_t)(gm2 - split) * K) + cofs;
    const u16* bp1 = Bb + (size_t)(n0 + rt) * K + cofs;
    const u16* bp2 = (TBN == 128) ? Bb + (size_t)(n0 + 64 + rt) * K + cofs : nullptr;

    u16* ldsA1 = &lds[tid * 8];          // rows 0..63
    u16* ldsA2 = &lds[2048 + tid * 8];   // rows 64..127
    u16* ldsB1 = &lds[4096 + tid * 8];
    u16* ldsB2 = &lds[6144 + tid * 8];

    const int wm = (w >> 1) * 64, wn = (w & 1) * (TBN / 2);
    const int fr = lane & 15;
    const int sw = (fr & 3) ^ ((fr >> 2) & 1);
    const int cread = (((lane >> 4) ^ sw) << 4);   // per-lane byte offset in row
    const char* ldsc = (const char*)lds;

    f32x4 acc[4][NT] = {};

    for (int k0 = 0; k0 < K; k0 += 32) {
        __syncthreads();
        gl16(ap1 + k0, ldsA1);
        gl16(ap2 + k0, ldsA2);
        gl16(bp1 + k0, ldsB1);
        if constexpr (TBN == 128) gl16(bp2 + k0, ldsB2);
        __syncthreads();   // drains vmcnt before fragment reads

        bf16x8 af[4], bfr[NT];
#pragma unroll
        for (int mt = 0; mt < 4; mt++)
            af[mt] = *(const bf16x8*)(ldsc + (((wm + mt * 16 + fr) << 6) | cread));
#pragma unroll
        for (int nt = 0; nt < NT; nt++)
            bfr[nt] = *(const bf16x8*)(ldsc + 8192 + (((wn + nt * 16 + fr) << 6) | cread));
#pragma unroll
        for (int mt = 0; mt < 4; mt++)
#pragma unroll
            for (int nt = 0; nt < NT; nt++)
                acc[mt][nt] = __builtin_amdgcn_mfma_f32_16x16x32_bf16(
                    af[mt], bfr[nt], acc[mt][nt], 0, 0, 0);
    }

    const int col = lane & 15, quad = lane >> 4;
#pragma unroll
    for (int mt = 0; mt < 4; mt++)
#pragma unroll
    for (int nt = 0; nt < NT; nt++)
#pragma unroll
    for (int r = 0; r < 4; r++) {
        const int m = m0 + wm + mt * 16 + quad * 4 + r;
        const int n = n0 + wn + nt * 16 + col;
        const float v = acc[mt][nt][r];
        if constexpr (EPIL == 0) {
            Cf[(size_t)m * N + n] = v;
        } else if constexpr (EPIL == 1) {
            Cf[(size_t)m * N + n] = v + bias[n];
        } else if constexpr (EPIL == 2) {
            Cb[(size_t)m * N + n] = f2b(fmaxf(v + bias[n], 0.f));
        } else if constexpr (EPIL == 3) {
            const int kl = m >> 5, b_ = m & 31;
            const int sec = n >> 9, cc = n & 511, hd = cc >> 6, dd = cc & 63;
            const int bh = b_ * H + hd;
            if (sec == 1) o3[((size_t)bh * KLEN + kl) * DH + dd] = f2b(v);
            else if (sec == 2) o4[((size_t)bh * KLEN + kl) * DH + dd] = f2b(v);  // natural V
            else if (kl >= MLEN) {
                const size_t qi = ((size_t)bh * QLEN + (kl - MLEN)) * DH + dd;
                Cb[qi] = f2b(v + rwb[hd * DH + dd]);
                o2[qi] = f2b(v + rrb[hd * DH + dd]);
            }
        } else if constexpr (EPIL == 4) {
            const int hd = n >> 6, dd = n & 63;
            Cb[(size_t)z * (H * KLEN * DH) +
               ((size_t)hd * KLEN + m) * DH + dd] = f2b(v);
        } else if constexpr (EPIL == 5) {
            Cb[(size_t)z * QLEN * SN + (size_t)m * SN + nOff + n] = f2b(v);
        } else if constexpr (EPIL == 6) {
            const int bn = bnBase + z;
            const int b_ = bn >> 3, nh = bn & 7;
            Cb[((size_t)m * BSZ + b_) * (H * DH) + nh * DH + n] = f2b(v);
        }
    }
}

// ---------- V transpose: v[bh][kl][dd] -> vt[bh][dd][kl] ----------
__global__ __launch_bounds__(256) void vtr_kernel(const u16* __restrict__ v,
                                                  u16* __restrict__ vt)
{
    __shared__ u16 t[32][33];
    const int bh = blockIdx.z;
    const int kl0 = blockIdx.x * 32, dd0 = blockIdx.y * 32;
    const int tx = threadIdx.x & 31, ty = threadIdx.x >> 5;   // 32x8
    const u16* src = v + (size_t)bh * KLEN * DH;
#pragma unroll
    for (int r = 0; r < 4; r++)
        t[ty + r * 8][tx] = src[(size_t)(kl0 + ty + r * 8) * DH + dd0 + tx];
    __syncthreads();
    u16* dst = vt + (size_t)bh * DH * KLEN;
#pragma unroll
    for (int r = 0; r < 4; r++)
        dst[(size_t)(dd0 + ty + r * 8) * KLEN + kl0 + tx] = t[tx][ty + r * 8];
}

// ---------- per-layer 4-weight transpose fp32[K][N] -> bf16[N][K] ----------
__global__ __launch_bounds__(256) void tr4_kernel(
    const float* __restrict__ s0, const float* __restrict__ s1,
    const float* __restrict__ s2, const float* __restrict__ s3,
    u16* __restrict__ d0, u16* __restrict__ d1, u16* __restrict__ d2,
    u16* __restrict__ d3)
{
    const float* src; u16* dst; int K, N;
    switch (blockIdx.z) {
        case 0: src = s0; dst = d0; K = 512;  N = 1536; break;
        case 1: src = s1; dst = d1; K = 512;  N = 512;  break;
        case 2: src = s2; dst = d2; K = 512;  N = 2048; break;
        default: src = s3; dst = d3; K = 2048; N = 512; break;
    }
    const int n0 = blockIdx.x * 32, k0 = blockIdx.y * 32;
    if (n0 >= N || k0 >= K) return;
    const int tx = threadIdx.x & 31, ty = threadIdx.x >> 5;
    __shared__ float t[32][33];
#pragma unroll
    for (int r = 0; r < 4; r++)
        t[ty + r * 8][tx] = src[(size_t)(k0 + ty + r * 8) * N + n0 + tx];
    __syncthreads();
#pragma unroll
    for (int r = 0; r < 4; r++)
        dst[(size_t)(n0 + ty + r * 8) * K + k0 + tx] = f2b(t[tx][ty + r * 8]);
}

// ---------- all-layer rnet transpose fp32[512][512] -> bf16[512][512] ----------
__global__ __launch_bounds__(256) void trrk_kernel(const float* __restrict__ s,
                                                   u16* __restrict__ d)
{
    const int l = blockIdx.z;
    const float* src = s + (size_t)l * DM * (H * DH);
    u16* dst = d + (size_t)l * DM * (H * DH);
    const int n0 = blockIdx.x * 32, k0 = blockIdx.y * 32;
    const int tx = threadIdx.x & 31, ty = threadIdx.x >> 5;
    __shared__ float t[32][33];
#pragma unroll
    for (int r = 0; r < 4; r++)
        t[ty + r * 8][tx] = src[(size_t)(k0 + ty + r * 8) * (H * DH) + n0 + tx];
    __syncthreads();
#pragma unroll
    for (int r = 0; r < 4; r++)
        dst[(size_t)(n0 + ty + r * 8) * DM + k0 + tx] = f2b(t[tx][ty + r * 8]);
}

// ---------- fp32 -> bf16 elementwise (x4) ----------
__global__ __launch_bounds__(256) void cvt4_kernel(const float* __restrict__ s,
                                                   u16* __restrict__ d)
{
    const int i = blockIdx.x * 256 + threadIdx.x;
    const float4 v = ((const float4*)s)[i];
    ((ushort4*)d)[i] = make_ushort4(f2b(v.x), f2b(v.y), f2b(v.z), f2b(v.w));
}

// ---------- copy fp32 + make bf16 copy ----------
__global__ __launch_bounds__(256) void copyh_kernel(const float* __restrict__ s,
                                                    float* __restrict__ h,
                                                    u16* __restrict__ hb)
{
    const int i = blockIdx.x * 256 + threadIdx.x;
    const float4 v = ((const float4*)s)[i];
    ((float4*)h)[i] = v;
    ((ushort4*)hb)[i] = make_ushort4(f2b(v.x), f2b(v.y), f2b(v.z), f2b(v.w));
}

// ---------- positional embedding r[KLEN][DM] bf16 ----------
__global__ __launch_bounds__(256) void r_kernel(u16* __restrict__ rb)
{
    const int idx = blockIdx.x * 256 + threadIdx.x;
    const int p = idx >> 9, c = idx & 511;
    const float pos = (float)(KLEN - 1 - p);
    const int i2 = (c < 256) ? c : (c - 256);
    const float invf = expf(-((float)(2 * i2) / (float)DM) * logf(10000.0f));
    const float a = pos * invf;
    rb[idx] = f2b((c < 256) ? sinf(a) : cosf(a));
}

// ---------- softmax: P = softmax((AC + shifted Srel)*scale), bf16 in/out ----------
__global__ __launch_bounds__(256) void softmax_kernel(const u16* __restrict__ S,
                                                      u16* __restrict__ P)
{
    const int r = blockIdx.x * 4 + (threadIdx.x >> 6);
    const int lane = threadIdx.x & 63;
    const int i = r & (QLEN - 1);
    const u16* sRow = S + (size_t)r * SN;
    u16* pRow = P + (size_t)r * KLEN;
    const int off = (QLEN - 1) - i;

    float v[8];
#pragma unroll
    for (int u = 0; u < 8; u++) {
        const int j = u * 64 + lane;
        v[u] = (j <= i + MLEN)
             ? (b2f(sRow[j]) + b2f(sRow[512 + j + off])) * SCALE : -1e30f;
    }
    float m = v[0];
#pragma unroll
    for (int u = 1; u < 8; u++) m = fmaxf(m, v[u]);
#pragma unroll
    for (int d = 32; d > 0; d >>= 1) m = fmaxf(m, __shfl_xor(m, d, 64));
    float s = 0.f;
#pragma unroll
    for (int u = 0; u < 8; u++) { v[u] = __expf(v[u] - m); s += v[u]; }
#pragma unroll
    for (int d = 32; d > 0; d >>= 1) s += __shfl_xor(s, d, 64);
    const float inv = 1.f / s;
#pragma unroll
    for (int u = 0; u < 8; u++) pRow[u * 64 + lane] = f2b(v[u] * inv);
}

// ---------- fused residual + LayerNorm, writes fp32 h and bf16 hb ----------
__global__ __launch_bounds__(256) void ln_kernel(
    float* __restrict__ h, u16* __restrict__ hb, const float* __restrict__ add,
    const float* __restrict__ g, const float* __restrict__ b)
{
    const int row = blockIdx.x;
    const int t = threadIdx.x;
    const size_t base = (size_t)row * DM;
    const float x0 = h[base + t] + add[base + t];
    const float x1 = h[base + t + 256] + add[base + t + 256];
    float s = x0 + x1;
    float s2 = x0 * x0 + x1 * x1;
#pragma unroll
    for (int off = 32; off > 0; off >>= 1) {
        s += __shfl_down(s, off, 64);
        s2 += __shfl_down(s2, off, 64);
    }
    __shared__ float ws1[4], ws2[4];
    const int wid = t >> 6, lane = t & 63;
    if (lane == 0) { ws1[wid] = s; ws2[wid] = s2; }
    __syncthreads();
    __shared__ float mv[2];
    if (t == 0) {
        float a = 0.f, a2 = 0.f;
        for (int wv = 0; wv < 4; wv++) { a += ws1[wv]; a2 += ws2[wv]; }
        const float mean = a / (float)DM;
        mv[0] = mean;
        mv[1] = rsqrtf(a2 / (float)DM - mean * mean + EPS);
    }
    __syncthreads();
    const float mean = mv[0], rstd = mv[1];
    const float r0 = (x0 - mean) * rstd * g[t] + b[t];
    const float r1 = (x1 - mean) * rstd * g[t + 256] + b[t + 256];
    h[base + t] = r0;
    h[base + t + 256] = r1;
    hb[base + t] = f2b(r0);
    hb[base + t + 256] = f2b(r1);
}

// ---------------- launcher ----------------
extern "C" void kernel_launch(void* const* d_in, const int* in_sizes, int n_in,
                              void* d_out, int out_size, void* d_ws, size_t ws_size,
                              hipStream_t stream)
{
    const float* w      = (const float*)d_in[0];
    const float* mems   = (const float*)d_in[1];
    const float* qkv_w  = (const float*)d_in[2];
    const float* rnet_w = (const float*)d_in[3];
    const float* o_w    = (const float*)d_in[4];
    const float* ln1_g  = (const float*)d_in[5];
    const float* ln1_b  = (const float*)d_in[6];
    const float* ff_w1  = (const float*)d_in[7];
    const float* ff_b1  = (const float*)d_in[8];
    const float* ff_w2  = (const float*)d_in[9];
    const float* ff_b2  = (const float*)d_in[10];
    const float* ln2_g  = (const float*)d_in[11];
    const float* ln2_b  = (const float*)d_in[12];
    const float* rwb    = (const float*)d_in[13];
    const float* rrb    = (const float*)d_in[14];

    char* p = (char*)d_ws;
    auto alloc = [&](size_t bytes) { void* r = p; p += (bytes + 255) & ~(size_t)255; return r; };

    const int HD = H * DH;   // 512

    float* hbuf  = (float*)alloc((size_t)QLEN * BSZ * DM * 4);
    u16*   hb    = (u16*)alloc((size_t)QLEN * BSZ * DM * 2);
    u16*   rb    = (u16*)alloc((size_t)KLEN * DM * 2);
    u16*   memsb = (u16*)alloc((size_t)MLEN * BSZ * DM * 2);
    u16*   qkvwt = (u16*)alloc((size_t)DM * 3 * HD * 2);
    u16*   owt   = (u16*)alloc((size_t)HD * DM * 2);
    u16*   f1wt  = (u16*)alloc((size_t)DM * DI * 2);
    u16*   f2wt  = (u16*)alloc((size_t)DI * DM * 2);
    u16*   rkwtA = (u16*)alloc((size_t)LNUM * DM * HD * 2);   // all layers
    u16*   rkbA  = (u16*)alloc((size_t)LNUM * H * KLEN * DH * 2);
    u16*   vecb  = (u16*)alloc((size_t)QLEN * BSZ * DM * 2);
    u16*   vtb   = (u16*)alloc((size_t)BSZ * H * DH * KLEN * 2);    // own buffer (r4 bug fix)
    char*  R1    = (char*)alloc((size_t)QLEN * BSZ * DM * 4);       // 16.8 MB
    char*  R2    = (char*)alloc((size_t)QLEN * BSZ * DI * 2);       // 33.6 MB
    u16*   qwb = (u16*)R1;
    u16*   qrb = (u16*)(R1 + (size_t)BSZ * H * QLEN * DH * 2);
    float* atmp = (float*)R1;     // alias: live after scores consumed
    float* ff2t = (float*)R1;
    u16*   kb  = (u16*)R2;
    u16*   vb  = (u16*)(R2 + (size_t)BSZ * H * KLEN * DH * 2);
    u16*   ff1b = (u16*)R2;       // alias: live after attention done

    const size_t used = (size_t)(p - (char*)d_ws);
    const size_t avail = ws_size > used ? ws_size - used : 0;
    int CH = 64;
    while (CH > 8 && (size_t)CH * ((size_t)QLEN * SN * 2 + (size_t)QLEN * KLEN * 2) > avail)
        CH >>= 1;
    u16* sbuf = (u16*)alloc((size_t)CH * QLEN * SN * 2);
    u16* pbuf = (u16*)alloc((size_t)CH * QLEN * KLEN * 2);

    const int BIG = 1 << 30;

    copyh_kernel<<<(QLEN * BSZ * DM) / 1024, 256, 0, stream>>>(w, hbuf, hb);
    r_kernel<<<(KLEN * DM) / 256, 256, 0, stream>>>(rb);
    trrk_kernel<<<dim3(16, 16, LNUM), 256, 0, stream>>>(rnet_w, rkwtA);
    // r_head_k for all layers: rb @ rnet_w[l], scatter to rkbA[l][h][pos][d]
    mm_bt<128, 4><<<dim3(4, 4, LNUM), 256, 0, stream>>>(
        rb, rb, BIG, rkwtA, nullptr,
        KLEN, HD, DM, 0, (long)DM * HD, 7,
        nullptr, rkbA, nullptr, nullptr, nullptr, nullptr, nullptr, nullptr, 0, 0);

    for (int l = 0; l < LNUM; l++) {
        cvt4_kernel<<<(MLEN * BSZ * DM) / 1024, 256, 0, stream>>>(
            mems + (size_t)l * MLEN * BSZ * DM, memsb);
        tr4_kernel<<<dim3(64, 64, 4), 256, 0, stream>>>(
            qkv_w + (size_t)l * DM * 3 * HD, o_w + (size_t)l * HD * DM,
            ff_w1 + (size_t)l * DM * DI, ff_w2 + (size_t)l * DI * DM,
            qkvwt, owt, f1wt, f2wt);

        // QKV with scatter epilogue (q biases folded, V natural)
        mm_bt<128, 3><<<dim3(12, 128, 1), 256, 0, stream>>>(
            memsb, hb, MLEN * BSZ, qkvwt, nullptr,
            KLEN * BSZ, 3 * HD, DM, 0, 0, 0,
            nullptr, qwb, nullptr, qrb, kb, vb, rwb, rrb, 0, 0);
        vtr_kernel<<<dim3(16, 2, BSZ * H), 256, 0, stream>>>(vb, vtb);

        const u16* rkbL = rkbA + (size_t)l * H * KLEN * DH;
        for (int bn0 = 0; bn0 < BSZ * H; bn0 += CH) {
            // AC (z<CH) and Srel (z>=CH) in one launch
            mm_bt<128, 5><<<dim3(4, 2, 2 * CH), 256, 0, stream>>>(
                qwb + (size_t)bn0 * QLEN * DH, qrb + (size_t)bn0 * QLEN * DH, BIG,
                kb + (size_t)bn0 * KLEN * DH, rkbL,
                QLEN, KLEN, DH, (long)QLEN * DH, (long)KLEN * DH, 0,
                nullptr, sbuf, nullptr, nullptr, nullptr, nullptr,
                nullptr, nullptr, bn0, CH);
            softmax_kernel<<<CH * 64, 256, 0, stream>>>(sbuf, pbuf);
            mm_bt<64, 6><<<dim3(1, 2, CH), 256, 0, stream>>>(
                pbuf, pbuf, BIG, vtb + (size_t)bn0 * DH * KLEN, nullptr,
                QLEN, DH, KLEN, (long)QLEN * KLEN, (long)DH * KLEN, 0x7FFFFFFF,
                nullptr, vecb, nullptr, nullptr, nullptr, nullptr,
                nullptr, nullptr, bn0, 0);
        }

        // O projection -> fp32 atmp
        mm_bt<128, 0><<<dim3(4, 64, 1), 256, 0, stream>>>(
            vecb, vecb, BIG, owt, nullptr,
            QLEN * BSZ, DM, HD, 0, 0, 0,
            atmp, nullptr, nullptr, nullptr, nullptr, nullptr, nullptr, nullptr, 0, 0);
        ln_kernel<<<QLEN * BSZ, 256, 0, stream>>>(hbuf, hb, atmp,
                                                  ln1_g + l * DM, ln1_b + l * DM);
        // FF1 (+bias+relu) -> bf16
        mm_bt<128, 2><<<dim3(16, 64, 1), 256, 0, stream>>>(
            hb, hb, BIG, f1wt, nullptr,
            QLEN * BSZ, DI, DM, 0, 0, 0,
            nullptr, ff1b, ff_b1 + (size_t)l * DI, nullptr, nullptr, nullptr,
            nullptr, nullptr, 0, 0);
        // FF2 (+bias) -> fp32
        mm_bt<128, 1><<<dim3(4, 64, 1), 256, 0, stream>>>(
            ff1b, ff1b, BIG, f2wt, nullptr,
            QLEN * BSZ, DM, DI, 0, 0, 0,
            ff2t, nullptr, ff_b2 + (size_t)l * DM, nullptr, nullptr, nullptr,
            nullptr, nullptr, 0, 0);
        ln_kernel<<<QLEN * BSZ, 256, 0, stream>>>(hbuf, hb, ff2t,
                                                  ln2_g + l * DM, ln2_b + l * DM);
    }
    hipMemcpyAsync(d_out, hbuf, (size_t)out_size * sizeof(float),
                   hipMemcpyDeviceToDevice, stream);
}